// Round 27
// baseline (18.890 us; speedup 1.0000x reference)
//
#include <hip/hip_runtime.h>
#include <hip/hip_fp16.h>
#include <math.h>

// GaussianMixtureLoss: loss = CONST - mean_{b,n}( ln sum_m exp(p·g - |g|²/2) - |p|²/2 )
// B=4, N=4096, M=4096, D=3, SIGMA=1.
// R27: fix the 50% grid-occupancy hole (R25: 512 blocks x 8 waves = 4096 of
// 8192 wave slots; R26's 16-wave blocks regressed). Split MIXTURES across
// blocks: 1024 blocks = 512 point-tiles x 2 mixture-halves; 512 thr, 16KB
// LDS -> 4 blocks/CU x 8 waves = 8 waves/SIMD. Same total MFMA+consume work
// as R23; K1 writes PRE-LOG partial sums pp[z][gp] (+ per-tile sum(hp2) in
// aux from z=0), K2 = one 1024-thr block: sum ln(pp0+pp1) - sum aux.
// MFMA Schraudolph algebra and C/D layout (m74/m101) unchanged from R23.
#define BATCH 4
#define NPTS 4096
#define NMIX 4096
#define THREADS 512
#define PPB 32                 // points per tile (one 32-row MFMA tile)
#define NTILE 512              // point tiles
#define NBLOCKS 1024           // 512 tiles x 2 mixture halves
#define MHALF 2048             // mixtures per block
#define NWAVES 8
#define TPW (MHALF / 32 / NWAVES)  // 8 mixture tiles per wave

#define LN2 0.6931471805599453f
#define CONST_TERM 0.9189385332046727f  // 0.5*log(2*pi)
#define INV_COUNT (1.0f / (float)(BATCH * NPTS))
// Schraudolph: K = 2^23*log2(e); BIAS = 2^23*(127-0.0563)
#define SQK      3478.8221f          // sqrt(K)
#define B4VAL    32768.0f            // exact in f16
#define A4BASE   32497.587f          // BIAS / 32768
#define A4SLOPE  (-184.66497f)       // -(K/2) / 32768

typedef _Float16 f16x4 __attribute__((ext_vector_type(4)));
typedef float f32x16 __attribute__((ext_vector_type(16)));

__device__ __forceinline__ float fast_log2(float x) {
#if __has_builtin(__builtin_amdgcn_logf)
  return __builtin_amdgcn_logf(x);
#else
  return log2f(x);
#endif
}

__device__ __forceinline__ uint32_t pack_h2(float a, float b) {
  __half2 h = __float22half2_rn(make_float2(a, b));
  return __builtin_bit_cast(uint32_t, h);
}

__global__ __launch_bounds__(THREADS) void gm_main(
    const float* __restrict__ pred, const float* __restrict__ gt,
    float* __restrict__ pp, float* __restrict__ aux) {
  __shared__ __align__(8) uint2 gsh[MHALF];  // 16 KB mixture f16 quads
  __shared__ float comb[NWAVES][PPB];        // 1 KB per-wave partial rows

  const int t = threadIdx.x;
  const int z = blockIdx.x >> 9;            // mixture half 0/1
  const int tile = blockIdx.x & 511;
  const int b = tile >> 7;                  // batch
  const int n0 = (tile & 127) * PPB;
  const int m0 = z * MHALF;
  const int lane = t & 63;
  const int w = t >> 6;                     // wave 0..7

  // ---- stage this half's mixture quads (sqrtK*g, a4), float2 pattern ----
#pragma unroll
  for (int i = 0; i < MHALF / (2 * THREADS); ++i) {  // 2 pairs per thread
    int s = t + i * THREADS;  // pair index 0..1023
    const float2* g =
        (const float2*)(gt + ((size_t)(b * NMIX + m0 + 2 * s)) * 3);
    float2 g01 = g[0], g23 = g[1], g45 = g[2];
    float n20 = fmaf(g01.x, g01.x, fmaf(g01.y, g01.y, g23.x * g23.x));
    float n21 = fmaf(g23.y, g23.y, fmaf(g45.x, g45.x, g45.y * g45.y));
    float a40 = fmaf(n20, A4SLOPE, A4BASE);
    float a41 = fmaf(n21, A4SLOPE, A4BASE);
    gsh[2 * s] = make_uint2(pack_h2(SQK * g01.x, SQK * g01.y),
                            pack_h2(SQK * g23.x, a40));
    gsh[2 * s + 1] = make_uint2(pack_h2(SQK * g23.y, SQK * g45.x),
                                pack_h2(SQK * g45.y, a41));
  }

  // ---- A-frag (points), loop-invariant: lane<32 -> point n0+lane ----
  f16x4 afrag;
  {
    uint2 au = make_uint2(0u, 0u);
    if (lane < 32) {
      const float* p = pred + (size_t)(b * NPTS + n0 + lane) * 3;
      au = make_uint2(pack_h2(SQK * p[0], SQK * p[1]),
                      pack_h2(SQK * p[2], B4VAL));
    }
    afrag = __builtin_bit_cast(f16x4, au);
  }

  __syncthreads();

  // ---- inner: 8 mixture tiles per wave, MFMA + Schraudolph cvt/add ----
  f32x16 acc = 0.0f;
  {
    const uint2* bbase = gsh + w * (TPW * 32) + (lane & 31);
    const bool lo = lane < 32;
    const f32x16 czero = 0.0f;
#pragma unroll 4
    for (int j = 0; j < TPW; ++j) {
      uint2 raw = bbase[j * 32];            // ds_read_b64
      raw.x = lo ? raw.x : 0u;              // zero k=4..7 lanes
      raw.y = lo ? raw.y : 0u;
      f16x4 bfrag = __builtin_bit_cast(f16x4, raw);
      f32x16 d = __builtin_amdgcn_mfma_f32_32x32x8f16(afrag, bfrag, czero, 0, 0, 0);
#pragma unroll
      for (int r = 0; r < 16; ++r)
        acc[r] += __builtin_bit_cast(float, (int)d[r]);  // Schraudolph exp
    }
  }

  // ---- col-reduce: sum 32 mixture-cols (xor over lane bits 0-4) ----
#pragma unroll
  for (int mask = 1; mask <= 16; mask <<= 1) {
#pragma unroll
    for (int r = 0; r < 16; ++r) acc[r] += __shfl_xor(acc[r], mask, 64);
  }

  // rows: (r&3) + 8*(r>>2) + 4*(lane>>5); lanes 0 and 32 write 16 rows each
  if ((lane & 31) == 0) {
#pragma unroll
    for (int r = 0; r < 16; ++r)
      comb[w][(r & 3) + 8 * (r >> 2) + 4 * (lane >> 5)] = acc[r];
  }
  __syncthreads();

  // ---- tail: combine 8 waves -> PRE-LOG partial sum per point ----
  if (t < PPB) {
    float s = ((comb[0][t] + comb[1][t]) + (comb[2][t] + comb[3][t])) +
              ((comb[4][t] + comb[5][t]) + (comb[6][t] + comb[7][t]));
    pp[(size_t)z * (BATCH * NPTS) + tile * PPB + t] = s;  // coalesced

    if (z == 0) {  // per-tile sum of |p|^2/2 (linearity)
      const float* p = pred + (size_t)(b * NPTS + n0 + t) * 3;
      float hp2 = 0.5f * (p[0] * p[0] + p[1] * p[1] + p[2] * p[2]);
#pragma unroll
      for (int off = 16; off > 0; off >>= 1)
        hp2 += __shfl_down(hp2, off, 32);
      if (t == 0) aux[tile] = hp2;
    }
  }
}

// K2: one 1024-thread block. total = sum_n ln(pp0[n]+pp1[n]) - sum aux;
// out = CONST - total/16384.
__global__ __launch_bounds__(1024) void gm_final(
    const float* __restrict__ pp, const float* __restrict__ aux,
    float* __restrict__ out) {
  const int t = threadIdx.x;
  const float* pp0 = pp;
  const float* pp1 = pp + BATCH * NPTS;

  float part = 0.f;
#pragma unroll
  for (int i = 0; i < (BATCH * NPTS) / 1024; ++i) {  // 16 coalesced iters
    int idx = t + i * 1024;
    part += fast_log2(pp0[idx] + pp1[idx]);
  }
  part *= LN2;
  if (t < NTILE) part -= aux[t];

  for (int off = 32; off > 0; off >>= 1) part += __shfl_down(part, off, 64);
  __shared__ float wred[16];
  if ((t & 63) == 0) wred[t >> 6] = part;
  __syncthreads();
  if (t < 16) {
    float v = wred[t];
#pragma unroll
    for (int off = 8; off > 0; off >>= 1) v += __shfl_down(v, off, 16);
    if (t == 0) out[0] = CONST_TERM - v * INV_COUNT;
  }
}

extern "C" void kernel_launch(void* const* d_in, const int* in_sizes, int n_in,
                              void* d_out, int out_size, void* d_ws, size_t ws_size,
                              hipStream_t stream) {
  const float* pred = (const float*)d_in[0];
  const float* gt   = (const float*)d_in[1];
  float* out = (float*)d_out;
  float* pp  = (float*)d_ws;                       // 2*16384 floats
  float* aux = pp + 2 * (BATCH * NPTS);            // +512 floats
  // all ws slots fully overwritten every call -> no init needed

  gm_main<<<NBLOCKS, THREADS, 0, stream>>>(pred, gt, pp, aux);
  gm_final<<<1, 1024, 0, stream>>>(pp, aux, out);
}

// Round 28
// 14.997 us; speedup vs baseline: 1.2596x; 1.2596x over previous
//
#include <hip/hip_runtime.h>
#include <hip/hip_fp16.h>
#include <math.h>

// GaussianMixtureLoss: loss = CONST - mean_{b,n}( ln sum_m exp(p·g - |g|²/2) - |p|²/2 )
// B=4, N=4096, M=4096, D=3, SIGMA=1.
// R28: REVERT to R23 (best measured: 15.03us). R24 (pipeline), R26 (16-wave
// blocks), R27 (mixture-split grid) all null/regressed - the MFMA-latency
// serialization is occupancy-immune, and restructures add more overhead
// than they recover. This is the validated best configuration:
//  - MFMA Schraudolph: quad (sqrtK*p,32768)x(sqrtK*g,a4) -> 32x32x8 f16
//    MFMA computes the Schraudolph-domain dot on the matrix pipe; VALU
//    keeps cvt+add (2 ops/exp). C/D layout per m74/m101.
//  - 512 blocks x 512 thr, 32KB LDS single-pass staging, 2 dispatches.
#define BATCH 4
#define NPTS 4096
#define NMIX 4096
#define THREADS 512
#define PPB 32                 // points per block (one 32-row MFMA tile)
#define NBLOCKS ((BATCH * NPTS) / PPB)  // 512
#define NTILES (NMIX / 32)     // 128 mixture tiles per batch
#define TPW (NTILES / 8)       // 16 tiles per wave (8 waves)

#define LN2 0.6931471805599453f
#define CONST_TERM 0.9189385332046727f  // 0.5*log(2*pi)
#define INV_COUNT (1.0f / (float)(BATCH * NPTS))
// Schraudolph: K = 2^23*log2(e) = 12102203.16; BIAS = 2^23*(127-0.0563)
#define SQK      3478.8221f          // sqrt(K)
#define B4VAL    32768.0f            // exact in f16
#define A4BASE   32497.587f          // BIAS / 32768
#define A4SLOPE  (-184.66497f)       // -(K/2) / 32768

typedef _Float16 f16x4 __attribute__((ext_vector_type(4)));
typedef float f32x16 __attribute__((ext_vector_type(16)));

__device__ __forceinline__ float fast_log2(float x) {
#if __has_builtin(__builtin_amdgcn_logf)
  return __builtin_amdgcn_logf(x);
#else
  return log2f(x);
#endif
}

__device__ __forceinline__ uint32_t pack_h2(float a, float b) {
  __half2 h = __float22half2_rn(make_float2(a, b));
  return __builtin_bit_cast(uint32_t, h);
}

__global__ __launch_bounds__(THREADS) void gm_main(
    const float* __restrict__ pred, const float* __restrict__ gt,
    float* __restrict__ bsum) {
  __shared__ __align__(8) uint2 gsh[NMIX];  // 32 KB: mixture f16 quads
  __shared__ float comb[8][PPB];            // 1 KB: per-wave partial rows

  const int t = threadIdx.x;
  const int b = blockIdx.x >> 7;            // 128 blocks per batch
  const int n0 = (blockIdx.x & 127) * PPB;
  const int lane = t & 63;
  const int w = t >> 6;                     // wave 0..7

  // ---- stage mixture table: quad (sqrtK*g, a4) as 4xf16 = 8 B ----
#pragma unroll
  for (int i = 0; i < NMIX / THREADS; ++i) {  // 8 per thread
    int m = t + i * THREADS;
    const float* g = gt + (size_t)(b * NMIX + m) * 3;
    float gx = g[0], gy = g[1], gz = g[2];
    float n2 = fmaf(gx, gx, fmaf(gy, gy, gz * gz));
    float a4 = fmaf(n2, A4SLOPE, A4BASE);
    gsh[m] = make_uint2(pack_h2(SQK * gx, SQK * gy), pack_h2(SQK * gz, a4));
  }

  // ---- A-frag (points), loop-invariant: lane<32 -> point n0+lane ----
  f16x4 afrag;
  {
    uint2 au = make_uint2(0u, 0u);
    if (lane < 32) {
      const float* p = pred + (size_t)(b * NPTS + n0 + lane) * 3;
      au = make_uint2(pack_h2(SQK * p[0], SQK * p[1]),
                      pack_h2(SQK * p[2], B4VAL));
    }
    afrag = __builtin_bit_cast(f16x4, au);
  }

  __syncthreads();

  // ---- inner: 16 mixture tiles per wave, MFMA + Schraudolph cvt/add ----
  f32x16 acc = 0.0f;
  {
    const uint2* bbase = gsh + w * (TPW * 32) + (lane & 31);
    const bool lo = lane < 32;
    const f32x16 czero = 0.0f;
#pragma unroll 4
    for (int j = 0; j < TPW; ++j) {
      uint2 raw = bbase[j * 32];            // ds_read_b64; upper lanes = broadcast dup
      raw.x = lo ? raw.x : 0u;              // zero k=4..7 lanes
      raw.y = lo ? raw.y : 0u;
      f16x4 bfrag = __builtin_bit_cast(f16x4, raw);
      f32x16 d = __builtin_amdgcn_mfma_f32_32x32x8f16(afrag, bfrag, czero, 0, 0, 0);
#pragma unroll
      for (int r = 0; r < 16; ++r)
        acc[r] += __builtin_bit_cast(float, (int)d[r]);  // Schraudolph exp
    }
  }

  // ---- col-reduce: sum the 32 mixture-cols (xor over lane bits 0-4) ----
#pragma unroll
  for (int mask = 1; mask <= 16; mask <<= 1) {
#pragma unroll
    for (int r = 0; r < 16; ++r) acc[r] += __shfl_xor(acc[r], mask, 64);
  }

  // rows: (r&3) + 8*(r>>2) + 4*(lane>>5); lanes 0 and 32 write 16 rows each
  if ((lane & 31) == 0) {
#pragma unroll
    for (int r = 0; r < 16; ++r)
      comb[w][(r & 3) + 8 * (r >> 2) + 4 * (lane >> 5)] = acc[r];
  }
  __syncthreads();

  // ---- tail: combine 8 waves, log, hp2, block reduce ----
  if (t < PPB) {
    float s = ((comb[0][t] + comb[1][t]) + (comb[2][t] + comb[3][t])) +
              ((comb[4][t] + comb[5][t]) + (comb[6][t] + comb[7][t]));
    const float* p = pred + (size_t)(b * NPTS + n0 + t) * 3;
    float hp2 = 0.5f * (p[0] * p[0] + p[1] * p[1] + p[2] * p[2]);
    float ll = (LN2 * fast_log2(s) - hp2) * INV_COUNT;
#pragma unroll
    for (int off = 16; off > 0; off >>= 1) ll += __shfl_down(ll, off, 32);
    if (t == 0) bsum[blockIdx.x] = ll;
  }
}

__global__ __launch_bounds__(256) void gm_reduce(
    const float* __restrict__ bsum, float* __restrict__ out) {
  const int t = threadIdx.x;
  float v = bsum[t] + bsum[t + 256];  // 512 entries
  for (int off = 32; off > 0; off >>= 1) v += __shfl_down(v, off, 64);
  __shared__ float w[4];
  if ((t & 63) == 0) w[t >> 6] = v;
  __syncthreads();
  if (t == 0) out[0] = CONST_TERM - ((w[0] + w[1]) + (w[2] + w[3]));
}

extern "C" void kernel_launch(void* const* d_in, const int* in_sizes, int n_in,
                              void* d_out, int out_size, void* d_ws, size_t ws_size,
                              hipStream_t stream) {
  const float* pred = (const float*)d_in[0];
  const float* gt   = (const float*)d_in[1];
  float* out = (float*)d_out;
  float* bsum = (float*)d_ws;  // 512 floats, fully overwritten every call

  gm_main<<<NBLOCKS, THREADS, 0, stream>>>(pred, gt, bsum);
  gm_reduce<<<1, 256, 0, stream>>>(bsum, out);
}